// Round 8
// baseline (17.369 us; speedup 1.0000x reference)
//
#include <hip/hip_runtime.h>

// Problem constants (match reference)
#define BATCH     16
#define SEQ_N     1024
#define EMBED_DIM 256
#define NTILE     32     // n-values per block -> NT store chunks are full 128B lines

typedef float f32x4 __attribute__((ext_vector_type(4)));

// out[b][d][n] = embedding[seq[b][n]][d]
//
// RULE (R6/R7 lesson): the gather row index MUST be wave-uniform — each wave
// loads exactly one 1KB embedding row as a lane-linear burst. Non-uniform row
// loads cost ~6-7us (R6: 16.3, R7: 17.1 vs R4: 10.1).
//
// Block = (b, n-tile of 32), 1024 threads. Grid 512 -> 2 blocks/CU x 16 waves
// = 32 waves/CU (max). LDS 32KB/block, XOR-swizzled (no pad):
//   element (row r, col d) at f4 slot r*64 + ((d>>2) ^ ((r>>2)&7)), word d&3
//   write: row uniform/wave -> lane permutation -> conflict-free ds_write_b128
//   read:  bank = 4*((d>>2)^q)+(d&3) over 8d x 8q lanes -> 2-way = free
// Stores: per d, 32 n = 128B full-line NT chunk (NT avoids RFO; R4-vs-R5 A/B).
__global__ __launch_bounds__(1024) void
embed_gather_transpose(const int* __restrict__ seq,
                       const float* __restrict__ emb,
                       float* __restrict__ out) {
    __shared__ f32x4 lds4[NTILE * 64];   // 32 KB
    const float* lds = reinterpret_cast<const float*>(lds4);

    const int b  = blockIdx.x >> 5;          // 16 batches
    const int n0 = (blockIdx.x & 31) << 5;   // 32 n-tiles of 32
    const int* seqb = seq + b * SEQ_N + n0;

    // ---- load phase: 32 rows x 64 f32x4 = 2048, 2/thread ----
    // nn = flat>>6 is wave-uniform; each wave-instr = one contiguous 1KB row.
#pragma unroll
    for (int i = 0; i < 2; ++i) {
        const int flat = i * 1024 + threadIdx.x;  // 0..2047
        const int nn   = flat >> 6;               // row in tile (wave-uniform)
        const int c4   = flat & 63;               // = lane
        const int row  = seqb[nn];
        lds4[nn * 64 + (c4 ^ ((nn >> 2) & 7))] =
            reinterpret_cast<const f32x4*>(emb + (size_t)row * EMBED_DIM)[c4];
    }
    __syncthreads();

    // ---- store phase: 256 d x 8 f32x4 (32 n) = 2048, 2/thread ----
    // 8 consecutive lanes emit one contiguous 128B line-aligned chunk per d.
    float* outb = out + ((size_t)b * EMBED_DIM) * SEQ_N + n0;
#pragma unroll
    for (int i = 0; i < 2; ++i) {
        const int flat = i * 1024 + threadIdx.x;  // 0..2047
        const int d    = flat >> 3;               // 0..255
        const int q    = flat & 7;                // f4 index within 32-n chunk
        f32x4 v;
#pragma unroll
        for (int k = 0; k < 4; ++k) {
            const int r = 4 * q + k;              // row in tile
            v[k] = lds[r * 256 + 4 * ((d >> 2) ^ ((r >> 2) & 7)) + (d & 3)];
        }
        __builtin_nontemporal_store(
            v, reinterpret_cast<f32x4*>(outb + (size_t)d * SEQ_N) + q);
    }
}

extern "C" void kernel_launch(void* const* d_in, const int* in_sizes, int n_in,
                              void* d_out, int out_size, void* d_ws, size_t ws_size,
                              hipStream_t stream) {
    const int*   seq = (const int*)d_in[0];
    const float* emb = (const float*)d_in[1];
    float*       out = (float*)d_out;

    const int grid = BATCH * (SEQ_N / NTILE);  // 16 * 32 = 512 blocks
    embed_gather_transpose<<<grid, 1024, 0, stream>>>(seq, emb, out);
}

// Round 9
// 10.127 us; speedup vs baseline: 1.7150x; 1.7150x over previous
//
#include <hip/hip_runtime.h>

// Problem constants (match reference)
#define BATCH     16
#define SEQ_N     1024
#define EMBED_DIM 256
#define NTILE     32     // n-rows per tile -> NT store chunks are full 128B lines
#define DHALF     128    // d-values stored per block

typedef float f32x4 __attribute__((ext_vector_type(4)));

// out[b][d][n] = embedding[seq[b][n]][d]
//
// Lessons enforced (R1..R8):
//  - gather row index wave-uniform: each wave-instr = one lane-linear 1KB row
//  - >=4 blocks/CU (4 barrier domains), 32 waves/CU
//  - NT stores (avoid RFO), now FULL 128B lines per chunk (test: R4's 64B
//    partial-line NT writes cost ~2x at the MC due to ECC RMW)
//
// Block = (b, n-tile of 32, d-half for STORES). Loads duplicate the full 32
// rows (1KB each); stores cover 128 d as 128B-line NT chunks. Grid 1024 x 512
// thr -> 4 blocks/CU (LDS 32KB, threads 2048) = 32 waves/CU, 4 domains.
// Pair-swizzle puts the two blocks sharing a tile on the SAME XCD (launch
// round-robin: bid and bid+8 -> same XCD) so the duplicate read L2-hits.
//
// LDS (32KB, no pad, XOR swizzle): element (r,d) at f4-slot r*64 +
// ((d>>2) ^ ((r>>2)&7)), word d&3.
//   write: r wave-uniform -> lane permutation -> conflict-free ds_write_b128
//   read:  per instr lanes (q in [0,8), dd in [0,8)): 2-way max = free
__global__ __launch_bounds__(512) void
embed_gather_transpose(const int* __restrict__ seq,
                       const float* __restrict__ emb,
                       float* __restrict__ out) {
    __shared__ f32x4 lds4[NTILE * 64];   // 32 KB
    const float* lds = reinterpret_cast<const float*>(lds4);

    // pair-swizzle: work p in [0,512), half h in {0,1}; bid=16m+8h+j -> p=8m+j
    const int bid = blockIdx.x;
    const int p   = ((bid >> 4) << 3) + (bid & 7);
    const int h   = (bid >> 3) & 1;

    const int b  = p >> 5;           // 16 batches
    const int n0 = (p & 31) << 5;    // 32 n-tiles of 32
    const int d0 = h << 7;           // d-half for stores

    const int* seqb = seq + b * SEQ_N + n0;

    // ---- load phase: 32 rows x 64 f32x4 = 2048, 4/thread ----
    // nn = flat>>6 wave-uniform; each wave-instr = one contiguous 1KB row.
#pragma unroll
    for (int i = 0; i < 4; ++i) {
        const int flat = i * 512 + threadIdx.x;   // 0..2047
        const int nn   = flat >> 6;               // row (wave-uniform)
        const int c4   = flat & 63;               // = lane
        const int row  = seqb[nn];
        lds4[nn * 64 + (c4 ^ ((nn >> 2) & 7))] =
            reinterpret_cast<const f32x4*>(emb + (size_t)row * EMBED_DIM)[c4];
    }
    __syncthreads();

    // ---- store phase: 128 d x 8 f32x4 (32 n) = 1024, 2/thread ----
    // 8 consecutive lanes emit one contiguous 128B full-line NT chunk per d.
    float* outb = out + ((size_t)b * EMBED_DIM + d0) * SEQ_N + n0;
#pragma unroll
    for (int j = 0; j < 2; ++j) {
        const int flat = j * 512 + threadIdx.x;   // 0..1023
        const int dd   = flat >> 3;               // 0..127 (local d)
        const int d    = d0 + dd;                 // global d (for LDS col)
        const int q    = flat & 7;                // f4 index within 32-n chunk
        f32x4 v;
#pragma unroll
        for (int k = 0; k < 4; ++k) {
            const int r = 4 * q + k;              // row in tile
            v[k] = lds[r * 256 + 4 * ((d >> 2) ^ ((r >> 2) & 7)) + (d & 3)];
        }
        __builtin_nontemporal_store(
            v, reinterpret_cast<f32x4*>(outb + (size_t)dd * SEQ_N) + q);
    }
}

extern "C" void kernel_launch(void* const* d_in, const int* in_sizes, int n_in,
                              void* d_out, int out_size, void* d_ws, size_t ws_size,
                              hipStream_t stream) {
    const int*   seq = (const int*)d_in[0];
    const float* emb = (const float*)d_in[1];
    float*       out = (float*)d_out;

    const int grid = BATCH * (SEQ_N / NTILE) * (EMBED_DIM / DHALF);  // 1024
    embed_gather_transpose<<<grid, 512, 0, stream>>>(seq, emb, out);
}